// Round 9
// baseline (146.846 us; speedup 1.0000x reference)
//
#include <hip/hip_runtime.h>
#include <hip/hip_bf16.h>

// SiameseConv: out[b,y,x,o] = sum_{i,j,c} det[b,y+i,x+j,c] * tmpl[b,i,j,c,o]
// det: [64,20,20,256] f32, tmpl: [64,4,4,256*20] f32, out: [64,17,17,20] f32.
//
// Per-example GEMM C[289x20] = A[289x4096] x B[4096x20], K=(ij,c), K-split by
// channel chunk of 32 -> 512 blocks; bf16 partials in d_ws.
// R9: single-kernel fusion WITHOUT cooperative launch (R8's coop launch fails
// under graph capture). Last-block-wins: per-b counter at ws+8MB; each block
// stores partials, __threadfence (release/L2-writeback), atomicAdd; the block
// seeing (old&7)==7 is last of its 8-block group -> atomicSub(8) (restores
// counter from ANY start value, incl 0xAA poison: olds are S..S+7, exactly one
// ==7 mod 8), __threadfence (acquire/L2-inv), reduces batch b. Deadlock-free
// (no spins); reduces overlap remaining GEMM blocks; deletes the 2nd dispatch
// + grid drain + flush boundary.

typedef __bf16 bf16x8 __attribute__((ext_vector_type(8)));
typedef float f32x4 __attribute__((ext_vector_type(4)));

#define NB 64
#define C_TOT 256
#define CQ 32            // channels per block
#define NQ 8             // c-chunks
#define NPOS 400         // 20*20 det positions
#define NP 289           // 17*17 output positions
#define NPP 296          // padded p stride in bf16 partials
#define NO 20            // outputs per position
#define OPAD 20          // o rows in LDS tmpl tile
#define QSTRIDE (NB * NO * NPP)             // elems per q slice = 378880
#define DET_LDS_BYTES (NPOS * CQ * 2)       // 25600: [400 pos][32 c]
#define TMP_LDS_BYTES (16 * OPAD * CQ * 2)  // 20480: [16 ij][20 o][32 c]
#define CTR_OFF (8u * 1024u * 1024u)        // counter region offset in ws

__device__ __forceinline__ unsigned short bfbits(float f) {
  __bf16 h = (__bf16)f;
  return __builtin_bit_cast(unsigned short, h);
}
__device__ __forceinline__ unsigned pk2(float a, float b) {
  return (unsigned)bfbits(a) | ((unsigned)bfbits(b) << 16);
}
__device__ __forceinline__ float lo2f(unsigned u) {
  return __builtin_bit_cast(float, u << 16);
}
__device__ __forceinline__ float hi2f(unsigned u) {
  return __builtin_bit_cast(float, u & 0xFFFF0000u);
}

__global__ __launch_bounds__(512, 2)
void siamese_fused(const float* __restrict__ det,
                   const float* __restrict__ tmp,
                   unsigned short* __restrict__ ws,
                   unsigned* __restrict__ counters,
                   float* __restrict__ out) {
  __shared__ alignas(16) char lds[DET_LDS_BYTES + TMP_LDS_BYTES];
  __shared__ unsigned oldv_sh;
  char* detB = lds;
  char* tmpB = lds + DET_LDS_BYTES;

  const int tid = threadIdx.x;
  const int b   = blockIdx.x >> 3;
  const int q   = blockIdx.x & 7;
  const int c0  = q * CQ;

  const float* __restrict__ dsrc = det + (size_t)b * (NPOS * C_TOT) + c0;
  const float* __restrict__ tsrc = tmp + (size_t)b * (16 * C_TOT * NO);

  // ==== PHASE 1: GEMM partials (verified R7 core, unchanged) ====

  // ---- det staging: 1600 units (pos, c-octet cp); 2 float4 loads ->
  // 1 ds_write_b128. byte = pos*64 + ((cp ^ ((pos>>1)&3))<<4).
  {
    #pragma unroll
    for (int k = 0; k < 3; ++k) {
      int u   = tid + k * 512;
      int pos = u >> 2, cp = u & 3;
      const float* s = dsrc + pos * C_TOT + cp * 8;
      float4 A = *(const float4*)s;
      float4 B = *(const float4*)(s + 4);
      uint4 w = { pk2(A.x, A.y), pk2(A.z, A.w), pk2(B.x, B.y), pk2(B.z, B.w) };
      *(uint4*)(detB + pos * 64 + ((cp ^ ((pos >> 1) & 3)) << 4)) = w;
    }
    if (tid < 64) {
      int u   = 1536 + tid;
      int pos = u >> 2, cp = u & 3;
      const float* s = dsrc + pos * C_TOT + cp * 8;
      float4 A = *(const float4*)s;
      float4 B = *(const float4*)(s + 4);
      uint4 w = { pk2(A.x, A.y), pk2(A.z, A.w), pk2(B.x, B.y), pk2(B.z, B.w) };
      *(uint4*)(detB + pos * 64 + ((cp ^ ((pos >> 1) & 3)) << 4)) = w;
    }
  }

  // ---- tmpl staging: 320 units (ij, c-octet co, o-quad oq). Load 8c x 4o,
  // register-transpose via cvt_pk, 4x ds_write_b128 into swizzled [ij][o][c]:
  // byte = ij*OPAD*64 + o*64 + ((co ^ ((o>>1)&3))<<4).
  if (tid < 320) {
    int ij = tid / 20;
    int r  = tid - ij * 20;
    int co = r / 5;
    int oq = r - co * 5;
    const float* s = tsrc + ij * (C_TOT * NO) + (c0 + co * 8) * NO + oq * 4;
    float4 v[8];
    #pragma unroll
    for (int rr = 0; rr < 8; ++rr) v[rr] = *(const float4*)(s + rr * NO);
    char* base = tmpB + ij * (OPAD * 64);
    #pragma unroll
    for (int k = 0; k < 4; ++k) {
      int o = oq * 4 + k;
      uint4 w;
      #define COMP(V) ((k == 0) ? (V).x : (k == 1) ? (V).y : (k == 2) ? (V).z : (V).w)
      w.x = pk2(COMP(v[0]), COMP(v[1]));
      w.y = pk2(COMP(v[2]), COMP(v[3]));
      w.z = pk2(COMP(v[4]), COMP(v[5]));
      w.w = pk2(COMP(v[6]), COMP(v[7]));
      #undef COMP
      *(uint4*)(base + o * 64 + ((co ^ ((o >> 1) & 3)) << 4)) = w;
    }
  }

  __syncthreads();

  // ---- compute: 19 M-tiles x 2 N-tiles over 8 waves, 16 K-steps of 32 ----
  {
    const int w    = tid >> 6;
    const int lane = tid & 63;
    const int lo   = lane & 15;
    const int hi   = lane >> 4;
    const int nm   = (w < 3) ? 3 : 2;   // tiles m = w + 8*mi: 3/3/3/2x5 = 19

    int posb[3];
    #pragma unroll
    for (int mi = 0; mi < 3; ++mi) {
      int m = w + mi * 8;
      int p = m * 16 + lo;
      if (p > NP - 1) p = NP - 1;        // clamp pad rows (masked at store)
      posb[mi] = (p / 17) * 20 + (p % 17);
    }

    f32x4 acc[3][2] = {};

    const int o0r  = lo;
    const int o1r  = (16 + lo < NO) ? (16 + lo) : (NO - 1);  // clamp pad cols
    const int bad0 = o0r * 64 + ((hi ^ ((o0r >> 1) & 3)) << 4);
    const int bad1 = o1r * 64 + ((hi ^ ((o1r >> 1) & 3)) << 4);

    for (int ij = 0; ij < 16; ++ij) {
      const int sh = (ij >> 2) * 20 + (ij & 3);

      bf16x8 bf0 = *(const bf16x8*)(tmpB + bad0 + ij * (OPAD * 64));
      bf16x8 bf1 = *(const bf16x8*)(tmpB + bad1 + ij * (OPAD * 64));

      #pragma unroll
      for (int mi = 0; mi < 3; ++mi) {
        if (mi < nm) {
          int pos  = posb[mi] + sh;
          int byte = pos * 64 + ((hi ^ ((pos >> 1) & 3)) << 4);
          bf16x8 a = *(const bf16x8*)(detB + byte);
          acc[mi][0] = __builtin_amdgcn_mfma_f32_16x16x32_bf16(a, bf0, acc[mi][0], 0, 0, 0);
          acc[mi][1] = __builtin_amdgcn_mfma_f32_16x16x32_bf16(a, bf1, acc[mi][1], 0, 0, 0);
        }
      }
    }

    // ---- store partials as packed bf16 into ws[q][b][o][p296] ----
    unsigned short* __restrict__ pws = ws + ((size_t)q * NB + b) * (NO * NPP);
    #pragma unroll
    for (int mi = 0; mi < 3; ++mi) {
      if (mi < nm) {
        int p0 = (w + mi * 8) * 16 + hi * 4;
        #pragma unroll
        for (int n = 0; n < 2; ++n) {
          int o = n * 16 + lo;
          if (o < NO) {
            if (p0 + 4 <= NP) {
              uint2 val = { pk2(acc[mi][n][0], acc[mi][n][1]),
                            pk2(acc[mi][n][2], acc[mi][n][3]) };
              *(uint2*)(pws + o * NPP + p0) = val;
            } else if (p0 < NP) {   // p0 == 288: single last position
              pws[o * NPP + p0] = bfbits(acc[mi][n][0]);
            }
          }
        }
      }
    }
  }

  // ==== group handshake: last block of the 8-block b-group reduces ====
  __threadfence();                       // release: partials visible device-wide
  if (tid == 0) {
    oldv_sh = atomicAdd(&counters[b * 16], 1u);
  }
  __syncthreads();                       // also: all waves done with LDS
  if ((oldv_sh & 7u) != 7u) return;      // not last -> done
  if (tid == 0) atomicSub(&counters[b * 16], 8u);   // restore start value
  __threadfence();                       // acquire: invalidate stale lines

  // ==== PHASE 2: reduce batch b (this block only) ====
  {
    float* sbuf = (float*)lds;           // [20 o][296 p] f32 = 23.7 KB
    // sum 8 q-slices: 20 o x 37 p-octets = 740 units
    for (int u = tid; u < NO * 37; u += 512) {
      int o  = u / 37;
      int po = u - o * 37;
      const unsigned short* src = ws + ((size_t)b * NO + o) * NPP + po * 8;
      float s[8] = {0, 0, 0, 0, 0, 0, 0, 0};
      #pragma unroll
      for (int qq = 0; qq < NQ; ++qq) {
        uint4 v = *(const uint4*)(src + (size_t)qq * QSTRIDE);
        s[0] += lo2f(v.x); s[1] += hi2f(v.x);
        s[2] += lo2f(v.y); s[3] += hi2f(v.y);
        s[4] += lo2f(v.z); s[5] += hi2f(v.z);
        s[6] += lo2f(v.w); s[7] += hi2f(v.w);
      }
      #pragma unroll
      for (int j = 0; j < 8; ++j) sbuf[o * 296 + po * 8 + j] = s[j];
    }
    __syncthreads();

    // transpose [o][p] -> [p][o], coalesced f32x4 writes
    for (int p = tid; p < NP; p += 512) {
      float* dst = out + (size_t)b * (NP * NO) + p * NO;
      #pragma unroll
      for (int k = 0; k < 5; ++k) {
        f32x4 v;
        #pragma unroll
        for (int j = 0; j < 4; ++j) v[j] = sbuf[(k * 4 + j) * 296 + p];
        *(f32x4*)(dst + k * 4) = v;
      }
    }
  }
}

extern "C" void kernel_launch(void* const* d_in, const int* in_sizes, int n_in,
                              void* d_out, int out_size, void* d_ws, size_t ws_size,
                              hipStream_t stream) {
  (void)in_sizes; (void)n_in; (void)out_size; (void)ws_size;
  const float* det = (const float*)d_in[0];
  const float* tmp = (const float*)d_in[1];
  float* out = (float*)d_out;
  unsigned short* ws = (unsigned short*)d_ws;            // 6.06 MB partials
  unsigned* counters = (unsigned*)((char*)d_ws + CTR_OFF); // 64 ctrs, 64B apart

  siamese_fused<<<dim3(NB * NQ), dim3(512), 0, stream>>>(det, tmp, ws,
                                                         counters, out);
}

// Round 10
// 21.916 us; speedup vs baseline: 6.7003x; 6.7003x over previous
//
#include <hip/hip_runtime.h>
#include <hip/hip_bf16.h>

// SiameseConv: out[b,y,x,o] = sum_{i,j,c} det[b,y+i,x+j,c] * tmpl[b,i,j,c,o]
// det: [64,20,20,256] f32, tmpl: [64,4,4,256*20] f32, out: [64,17,17,20] f32.
//
// Per-example GEMM C[289x20] = A[289x4096] x B[4096x20], K=(ij,c), K-split by
// channel chunk of 32 -> 512 blocks; bf16 partials in d_ws + reduce kernel.
// R2: atomics removed (cross-XCD contention ~37us). R9 post-mortem: fences in
// kernel = full-L2 wbinv per wave = 7x slowdown -> fusion abandoned; node
// overhead measured ~0.3us (R3->R7), so 2-kernel structure stands.
// R10: revert to R7 + BURST STAGING: issue ALL ~16 global dwordx4 loads per
// thread back-to-back (det then tmpl) BEFORE any LDS writes, so counted
// vmcnt waits overlap tmpl HBM fetch with det convert/ds_write (inputs come
// from HBM each replay: harness reset() refills 268MB ws between iterations,
// thrashing L3).

typedef __bf16 bf16x8 __attribute__((ext_vector_type(8)));
typedef float f32x4 __attribute__((ext_vector_type(4)));

#define NB 64
#define C_TOT 256
#define CQ 32            // channels per block
#define NQ 8             // c-chunks
#define NPOS 400         // 20*20 det positions
#define NP 289           // 17*17 output positions
#define NPP 296          // padded p stride in bf16 partials
#define NO 20            // outputs per position
#define OPAD 20          // o rows in LDS tmpl tile
#define QSTRIDE (NB * NO * NPP)             // elems per q slice = 378880
#define DET_LDS_BYTES (NPOS * CQ * 2)       // 25600: [400 pos][32 c]
#define TMP_LDS_BYTES (16 * OPAD * CQ * 2)  // 20480: [16 ij][20 o][32 c]

__device__ __forceinline__ unsigned short bfbits(float f) {
  __bf16 h = (__bf16)f;
  return __builtin_bit_cast(unsigned short, h);
}
__device__ __forceinline__ unsigned pk2(float a, float b) {
  return (unsigned)bfbits(a) | ((unsigned)bfbits(b) << 16);
}
__device__ __forceinline__ float lo2f(unsigned u) {
  return __builtin_bit_cast(float, u << 16);
}
__device__ __forceinline__ float hi2f(unsigned u) {
  return __builtin_bit_cast(float, u & 0xFFFF0000u);
}

// ---- reduce: out[b,p,o] = sum_q bf16 ws[q,b,o,p]; transpose via LDS ----
// grid: (b, p-group of 80) = 64*4 blocks, 256 threads.
__global__ __launch_bounds__(256)
void reduce_kernel(const unsigned short* __restrict__ ws, float* __restrict__ out) {
  __shared__ float sbuf[NO * 80];   // [o][80 p]
  const int b    = blockIdx.x >> 2;
  const int pg   = blockIdx.x & 3;
  const int p0g  = pg * 80;
  const int np   = (NP - p0g < 80) ? (NP - p0g) : 80;   // 80,80,80,49
  const int noct = (np + 7) >> 3;                       // 10 or 7
  const int units = NO * noct;                          // 200 or 140

  const int t = threadIdx.x;
  if (t < units) {
    int o  = t / noct;
    int po = t - o * noct;
    const unsigned short* src = ws + ((size_t)b * NO + o) * NPP + p0g + po * 8;
    float s[8] = {0, 0, 0, 0, 0, 0, 0, 0};
    #pragma unroll
    for (int q = 0; q < NQ; ++q) {
      uint4 v = *(const uint4*)(src + (size_t)q * QSTRIDE);
      s[0] += lo2f(v.x); s[1] += hi2f(v.x);
      s[2] += lo2f(v.y); s[3] += hi2f(v.y);
      s[4] += lo2f(v.z); s[5] += hi2f(v.z);
      s[6] += lo2f(v.w); s[7] += hi2f(v.w);
    }
    #pragma unroll
    for (int j = 0; j < 8; ++j) sbuf[o * 80 + po * 8 + j] = s[j];
  }
  __syncthreads();

  for (int p = t; p < np; p += 256) {
    float* dst = out + (size_t)b * (NP * NO) + (p0g + p) * NO;
    #pragma unroll
    for (int k = 0; k < 5; ++k) {
      f32x4 v;
      #pragma unroll
      for (int j = 0; j < 4; ++j) v[j] = sbuf[(k * 4 + j) * 80 + p];
      *(f32x4*)(dst + k * 4) = v;
    }
  }
}

__global__ __launch_bounds__(512, 2)
void siamese_kernel(const float* __restrict__ det,
                    const float* __restrict__ tmp,
                    unsigned short* __restrict__ ws) {
  __shared__ alignas(16) char lds[DET_LDS_BYTES + TMP_LDS_BYTES];
  char* detB = lds;
  char* tmpB = lds + DET_LDS_BYTES;

  const int tid = threadIdx.x;
  const int b   = blockIdx.x >> 3;
  const int q   = blockIdx.x & 7;
  const int c0  = q * CQ;

  const float* __restrict__ dsrc = det + (size_t)b * (NPOS * C_TOT) + c0;
  const float* __restrict__ tsrc = tmp + (size_t)b * (16 * C_TOT * NO);

  // ==== BURST STAGING: issue ALL global loads, then all LDS writes ====
  // det units (pos, c-octet cp): u = tid + k*512 (k<3) + tail u=1536+tid
  // (tid<64). tmpl units (ij, c-octet co, o-quad oq): tid<320.
  float4 dva[4][2];
  int dpos[4] = {0, 0, 0, 0}, dcp[4] = {0, 0, 0, 0};
  #pragma unroll
  for (int k = 0; k < 3; ++k) {
    int u = tid + k * 512;
    dpos[k] = u >> 2; dcp[k] = u & 3;
    const float* s = dsrc + dpos[k] * C_TOT + dcp[k] * 8;
    dva[k][0] = *(const float4*)s;
    dva[k][1] = *(const float4*)(s + 4);
  }
  if (tid < 64) {   // wave 0 only (uniform branch)
    int u = 1536 + tid;
    dpos[3] = u >> 2; dcp[3] = u & 3;
    const float* s = dsrc + dpos[3] * C_TOT + dcp[3] * 8;
    dva[3][0] = *(const float4*)s;
    dva[3][1] = *(const float4*)(s + 4);
  }
  int t_ij = 0, t_co = 0, t_oq = 0;
  float4 tv[8];
  if (tid < 320) {  // waves 0-4 only (uniform branch)
    t_ij = tid / 20;
    int r = tid - t_ij * 20;
    t_co = r / 5;
    t_oq = r - t_co * 5;
    const float* s = tsrc + t_ij * (C_TOT * NO) + (c0 + t_co * 8) * NO + t_oq * 4;
    #pragma unroll
    for (int rr = 0; rr < 8; ++rr) tv[rr] = *(const float4*)(s + rr * NO);
  }

  // det writes: byte = pos*64 + ((cp ^ ((pos>>1)&3))<<4)
  #pragma unroll
  for (int k = 0; k < 3; ++k) {
    uint4 w = { pk2(dva[k][0].x, dva[k][0].y), pk2(dva[k][0].z, dva[k][0].w),
                pk2(dva[k][1].x, dva[k][1].y), pk2(dva[k][1].z, dva[k][1].w) };
    *(uint4*)(detB + dpos[k] * 64 + ((dcp[k] ^ ((dpos[k] >> 1) & 3)) << 4)) = w;
  }
  if (tid < 64) {
    uint4 w = { pk2(dva[3][0].x, dva[3][0].y), pk2(dva[3][0].z, dva[3][0].w),
                pk2(dva[3][1].x, dva[3][1].y), pk2(dva[3][1].z, dva[3][1].w) };
    *(uint4*)(detB + dpos[3] * 64 + ((dcp[3] ^ ((dpos[3] >> 1) & 3)) << 4)) = w;
  }
  // tmpl writes: register-transpose 8c x 4o -> 4x ds_write_b128 into
  // swizzled [ij][o][c]: byte = ij*OPAD*64 + o*64 + ((co ^ ((o>>1)&3))<<4)
  if (tid < 320) {
    char* base = tmpB + t_ij * (OPAD * 64);
    #pragma unroll
    for (int k = 0; k < 4; ++k) {
      int o = t_oq * 4 + k;
      uint4 w;
      #define COMP(V) ((k == 0) ? (V).x : (k == 1) ? (V).y : (k == 2) ? (V).z : (V).w)
      w.x = pk2(COMP(tv[0]), COMP(tv[1]));
      w.y = pk2(COMP(tv[2]), COMP(tv[3]));
      w.z = pk2(COMP(tv[4]), COMP(tv[5]));
      w.w = pk2(COMP(tv[6]), COMP(tv[7]));
      #undef COMP
      *(uint4*)(base + o * 64 + ((t_co ^ ((o >> 1) & 3)) << 4)) = w;
    }
  }

  __syncthreads();

  // ---- compute: 19 M-tiles x 2 N-tiles over 8 waves, 16 K-steps of 32 ----
  const int w    = tid >> 6;
  const int lane = tid & 63;
  const int lo   = lane & 15;
  const int hi   = lane >> 4;
  const int nm   = (w < 3) ? 3 : 2;   // tiles m = w + 8*mi: 3/3/3/2x5 = 19

  int posb[3];
  #pragma unroll
  for (int mi = 0; mi < 3; ++mi) {
    int m = w + mi * 8;
    int p = m * 16 + lo;
    if (p > NP - 1) p = NP - 1;        // clamp pad rows (masked at store)
    posb[mi] = (p / 17) * 20 + (p % 17);
  }

  f32x4 acc[3][2] = {};

  const int o0r  = lo;
  const int o1r  = (16 + lo < NO) ? (16 + lo) : (NO - 1);  // clamp pad cols
  const int bad0 = o0r * 64 + ((hi ^ ((o0r >> 1) & 3)) << 4);
  const int bad1 = o1r * 64 + ((hi ^ ((o1r >> 1) & 3)) << 4);

  for (int ij = 0; ij < 16; ++ij) {
    const int sh = (ij >> 2) * 20 + (ij & 3);

    bf16x8 bf0 = *(const bf16x8*)(tmpB + bad0 + ij * (OPAD * 64));
    bf16x8 bf1 = *(const bf16x8*)(tmpB + bad1 + ij * (OPAD * 64));

    #pragma unroll
    for (int mi = 0; mi < 3; ++mi) {
      if (mi < nm) {
        int pos  = posb[mi] + sh;
        int byte = pos * 64 + ((hi ^ ((pos >> 1) & 3)) << 4);
        bf16x8 a = *(const bf16x8*)(detB + byte);
        acc[mi][0] = __builtin_amdgcn_mfma_f32_16x16x32_bf16(a, bf0, acc[mi][0], 0, 0, 0);
        acc[mi][1] = __builtin_amdgcn_mfma_f32_16x16x32_bf16(a, bf1, acc[mi][1], 0, 0, 0);
      }
    }
  }

  // ---- store partials as packed bf16 uint2 into ws[q][b][o][p296] ----
  // C/D frag: col(o)=lane&15, row(p)=(lane>>4)*4+reg -> reg v is contiguous p.
  unsigned short* __restrict__ pws = ws + ((size_t)q * NB + b) * (NO * NPP);
  #pragma unroll
  for (int mi = 0; mi < 3; ++mi) {
    if (mi < nm) {
      int p0 = (w + mi * 8) * 16 + hi * 4;
      #pragma unroll
      for (int n = 0; n < 2; ++n) {
        int o = n * 16 + lo;
        if (o < NO) {
          if (p0 + 4 <= NP) {
            uint2 val = { pk2(acc[mi][n][0], acc[mi][n][1]),
                          pk2(acc[mi][n][2], acc[mi][n][3]) };
            *(uint2*)(pws + o * NPP + p0) = val;
          } else if (p0 < NP) {   // p0 == 288: single last position
            pws[o * NPP + p0] = bfbits(acc[mi][n][0]);
          }
        }
      }
    }
  }
}

extern "C" void kernel_launch(void* const* d_in, const int* in_sizes, int n_in,
                              void* d_out, int out_size, void* d_ws, size_t ws_size,
                              hipStream_t stream) {
  (void)in_sizes; (void)n_in; (void)out_size; (void)ws_size;
  const float* det = (const float*)d_in[0];
  const float* tmp = (const float*)d_in[1];
  float* out = (float*)d_out;
  unsigned short* ws = (unsigned short*)d_ws;   // 8*64*20*296*2B = 6.06 MB

  siamese_kernel<<<dim3(NB * NQ), dim3(512), 0, stream>>>(det, tmp, ws);
  reduce_kernel<<<dim3(NB * 4), dim3(256), 0, stream>>>(ws, out);
}